// Round 5
// baseline (223.359 us; speedup 1.0000x reference)
//
#include <hip/hip_runtime.h>
#include <stdint.h>

// T5-style attention, MI355X gfx950.
// B=2 S=2048 D=1024 H=16 DK=64, NUM_BUCKETS=32, MAX_DISTANCE=128.
// R5: flash v4 — KT=128 staging (half the barriers), ds_read2-paired bias
// reads, exp2+fma fold (log2e baked into bias table), f-interleaved MFMA.

typedef unsigned short u16;
typedef __attribute__((ext_vector_type(8))) short short8;
typedef __attribute__((ext_vector_type(4))) float float4v;
typedef __attribute__((ext_vector_type(4))) u16 ushort4v;

typedef __attribute__((address_space(1))) void void_g;
typedef __attribute__((address_space(3))) void void_l;

#define L2E 1.4426950408889634f

__device__ __forceinline__ u16 f2b(float f) {
  union { float f; uint32_t u; } v; v.f = f;
  uint32_t r = (v.u + 0x7fffu + ((v.u >> 16) & 1u)) >> 16;
  return (u16)r;
}
__device__ __forceinline__ u16 f2b_fast(float f) {
  union { float f; uint32_t u; } v; v.f = f;
  return (u16)((v.u + 0x8000u) >> 16);
}

// ---------------- fused fp32 -> bf16 convert -----------------------------------
// float4 regions: x 1048576 | q_w 262144 | k_w 262144 | v_w 262144 | o_w 262144
__global__ void cvt_all(const float* __restrict__ x,  const float* __restrict__ qw,
                        const float* __restrict__ kw, const float* __restrict__ vw,
                        const float* __restrict__ ow,
                        u16* __restrict__ xb, u16* __restrict__ wqkv, u16* __restrict__ owb) {
  int i = blockIdx.x * blockDim.x + threadIdx.x;
  const float* s; u16* d; int off;
  if (i < 1048576)      { s = x;  d = xb;              off = i; }
  else if (i < 1310720) { s = qw; d = wqkv;            off = i - 1048576; }
  else if (i < 1572864) { s = kw; d = wqkv + 1048576;  off = i - 1310720; }
  else if (i < 1835008) { s = vw; d = wqkv + 2097152;  off = i - 1572864; }
  else                  { s = ow; d = owb;             off = i - 1835008; }
  float4v v = ((const float4v*)s)[off];
  ushort4v o;
  o.x = f2b(v.x); o.y = f2b(v.y); o.z = f2b(v.z); o.w = f2b(v.w);
  ((ushort4v*)d)[off] = o;
}

// ---------------- bias table: biasT[h][d+2047] = (bias - 8) * log2e ------------
__global__ void build_bias(const float* __restrict__ rel_bias, float* __restrict__ biasT) {
  int idx = blockIdx.x * blockDim.x + threadIdx.x; // 16 * 4096
  int h = idx >> 12, t = idx & 4095;
  if (t > 4094) { biasT[h * 4096 + 4095] = -1.0e4f; return; }  // unused, keep finite
  int d = t - 2047;
  int n = -d;
  int ret = (n < 0) ? 16 : 0;
  int na = (n < 0) ? -n : n;
  int bucket;
  if (na < 8) {
    bucket = ret + na;
  } else {
    float v = logf((float)na / 8.0f) / logf(16.0f) * 8.0f;
    int vi = 8 + (int)v;
    bucket = ret + (vi > 15 ? 15 : vi);
  }
  biasT[h * 4096 + t] = (rel_bias[bucket * 16 + h] - 8.0f) * L2E;
}

// ---------------- bf16 GEMM: C[M,N] = A[M,K] * W[N,K]^T ------------------------
template<bool OUT_BF16>
__global__ __launch_bounds__(256, 2)
void gemm_bt(const u16* __restrict__ A, const u16* __restrict__ W,
             void* __restrict__ Cp, int K, int N) {
  __shared__ __align__(16) u16 As[128 * 32];
  __shared__ __align__(16) u16 Bs[128 * 32];
  const int tid = threadIdx.x;
  const int wid = tid >> 6;
  const int lane = tid & 63;
  const int row16 = lane & 15, oct = lane >> 4;
  const int tm = blockIdx.x * 128, tn = blockIdx.y * 128;
  const int wm = (wid & 1) * 64, wn = (wid >> 1) * 64;
  float4v acc[4][4] = {};
  for (int k0 = 0; k0 < K; k0 += 32) {
    __syncthreads();
#pragma unroll
    for (int i = 0; i < 2; i++) {
      const int fo = (i * 256 + tid) * 8;
      const int r = fo >> 5, c = fo & 31;
      __builtin_amdgcn_global_load_lds((void_g*)(A + (size_t)(tm + r) * K + k0 + c),
                                       (void_l*)(As + (i * 256 + wid * 64) * 8), 16, 0, 0);
      __builtin_amdgcn_global_load_lds((void_g*)(W + (size_t)(tn + r) * K + k0 + c),
                                       (void_l*)(Bs + (i * 256 + wid * 64) * 8), 16, 0, 0);
    }
    __syncthreads();
    short8 af[4], bfr[4];
#pragma unroll
    for (int mi = 0; mi < 4; mi++)
      af[mi] = *(const short8*)(As + (wm + mi * 16 + row16) * 32 + oct * 8);
#pragma unroll
    for (int ni = 0; ni < 4; ni++)
      bfr[ni] = *(const short8*)(Bs + (wn + ni * 16 + row16) * 32 + oct * 8);
#pragma unroll
    for (int mi = 0; mi < 4; mi++)
#pragma unroll
      for (int ni = 0; ni < 4; ni++)
        acc[mi][ni] = __builtin_amdgcn_mfma_f32_16x16x32_bf16(af[mi], bfr[ni], acc[mi][ni], 0, 0, 0);
  }
#pragma unroll
  for (int mi = 0; mi < 4; mi++) {
    const int rbase = tm + wm + mi * 16 + oct * 4;
#pragma unroll
    for (int ni = 0; ni < 4; ni++) {
      const int col = tn + wn + ni * 16 + row16;
#pragma unroll
      for (int r = 0; r < 4; r++) {
        size_t idx = (size_t)(rbase + r) * N + col;
        if (OUT_BF16) ((u16*)Cp)[idx] = f2b(acc[mi][ni][r]);
        else          ((float*)Cp)[idx] = acc[mi][ni][r];
      }
    }
  }
}

// ---------------- V transpose + k-permutation ----------------------------------
// QKV V-section [b][s][h*64+d] -> vTp[b][h][d][s'], kappa = 2*(s&15)+((s>>4)&1)
// within each 32-block of s (matches flash's packed-P k order).
__global__ __launch_bounds__(256, 2)
void transpose_v(const u16* __restrict__ QKV, u16* __restrict__ vTp) {
  const int s0 = blockIdx.x * 64, h = blockIdx.y, b = blockIdx.z;
  const int tid = threadIdx.x;
  __shared__ u16 T[64 * 73];
  const u16* src = QKV + 2048 + (size_t)b * 2048 * 3072 + h * 64;
#pragma unroll
  for (int it = 0; it < 2; it++) {
    int idx = it * 256 + tid;
    int sl = idx >> 3;
    int c = idx & 7;
    short8 v = *(const short8*)(src + (size_t)(s0 + sl) * 3072 + c * 8);
#pragma unroll
    for (int k = 0; k < 8; k++) T[(c * 8 + k) * 73 + sl] = (u16)v[k];
  }
  __syncthreads();
  u16* dst = vTp + ((size_t)(b * 16 + h) * 64) * 2048 + s0;
#pragma unroll
  for (int it = 0; it < 2; it++) {
    int idx = it * 256 + tid;
    int d = idx >> 3;
    int cs = idx & 7;
    short8 o;
#pragma unroll
    for (int k = 0; k < 8; k++) {
      int sp = cs * 8 + k;
      int sl = (sp & 32) + 16 * (sp & 1) + ((sp & 31) >> 1);
      o[k] = (short)T[d * 73 + sl];
    }
    *(short8*)(dst + (size_t)d * 2048 + cs * 8) = o;
  }
}

// ---------------- flash attention v4 -------------------------------------------
// grid (S/128, H, B), block 256 = 4 waves; wave owns 32 q-rows (2 q-frags).
// KT=128 staged tile, processed in two 64-col halves. Static softmax max 8,
// exp2-folded (bias table pre-multiplied by log2e).
__global__ __launch_bounds__(256, 2)
void flash_attn(const u16* __restrict__ QKV, const u16* __restrict__ vTp,
                const float* __restrict__ biasT, u16* __restrict__ ctx) {
  const int S = 2048, LDQ = 3072;
  const int qt0 = blockIdx.x * 128;
  const int h = blockIdx.y, b = blockIdx.z;
  const int tid = threadIdx.x, wid = tid >> 6, lane = tid & 63;
  const int row16 = lane & 15, oct = lane >> 4;

  __shared__ __align__(16) float biasS[2176];        // 8.5 KB window (pre *log2e, -8 folded)
  __shared__ __align__(16) u16 Ks[2][128][40];       // 20 KB [d-half][kcol][d%32] pad 40
  __shared__ __align__(16) u16 Vts[4][64][40];       // 20 KB [k-chunk][d][kappa] pad 40
  __shared__ __align__(16) u16 Pl[4][2][16][40];     // 10 KB per-wave P staging

  {
    const float* bsrc = biasT + h * 4096 + (1920 - qt0);
    for (int i = tid; i < 544; i += 256)
      ((float4v*)biasS)[i] = ((const float4v*)bsrc)[i];
  }

  // Q fragments: 2 q-frags x 2 d-halves
  const u16* qbase = QKV + ((size_t)b * S + qt0 + wid * 32) * LDQ + h * 64;
  short8 qf[2][2];
#pragma unroll
  for (int f = 0; f < 2; f++)
#pragma unroll
    for (int hd = 0; hd < 2; hd++)
      qf[f][hd] = *(const short8*)(qbase + (size_t)(f * 16 + row16) * LDQ + hd * 32 + oct * 8);

  float l_r[2][4] = {};
  float4v o_acc[2][4] = {};

  // staging: K rows wid*32+rr*16+sr (rr=0,1); V d-rows wid*16+sr; chunk c8
  const int sr = lane >> 2, c8 = (lane & 3) * 8;
  const u16* Kst = QKV + 1024 + ((size_t)b * S + wid * 32 + sr) * LDQ + h * 64 + c8;
  const u16* Vst = vTp + ((size_t)(b * 16 + h) * 64 + wid * 16 + sr) * 2048 + c8;

  short8 kreg[2][2], vreg[4];
#pragma unroll
  for (int rr = 0; rr < 2; rr++)
#pragma unroll
    for (int hd = 0; hd < 2; hd++)
      kreg[rr][hd] = *(const short8*)(Kst + (size_t)(rr * 16) * LDQ + hd * 32);
#pragma unroll
  for (int ks = 0; ks < 4; ks++) vreg[ks] = *(const short8*)(Vst + ks * 32);

  for (int kt = 0; kt < S; kt += 128) {
    __syncthreads();  // prev tile consumed
#pragma unroll
    for (int rr = 0; rr < 2; rr++)
#pragma unroll
      for (int hd = 0; hd < 2; hd++)
        *(short8*)&Ks[hd][wid * 32 + rr * 16 + sr][c8] = kreg[rr][hd];
#pragma unroll
    for (int ks = 0; ks < 4; ks++) *(short8*)&Vts[ks][wid * 16 + sr][c8] = vreg[ks];
    __syncthreads();  // tile ready

    if (kt + 128 < S) {  // software prefetch next tile
#pragma unroll
      for (int rr = 0; rr < 2; rr++)
#pragma unroll
        for (int hd = 0; hd < 2; hd++)
          kreg[rr][hd] = *(const short8*)(Kst + (size_t)(kt + 128 + rr * 16) * LDQ + hd * 32);
#pragma unroll
      for (int ks = 0; ks < 4; ks++)
        vreg[ks] = *(const short8*)(Vst + (kt + 128) + ks * 32);
    }

#pragma unroll
    for (int half = 0; half < 2; half++) {
      // K fragments for this 64-col half (shared by both q-frags)
      short8 kf[4][2];
#pragma unroll
      for (int st = 0; st < 4; st++)
#pragma unroll
        for (int hd = 0; hd < 2; hd++)
          kf[st][hd] = *(const short8*)&Ks[hd][half * 64 + st * 16 + row16][oct * 8];

      // scores for both q-frags (independent MFMA chains)
      float4v sc[2][4];
#pragma unroll
      for (int f = 0; f < 2; f++)
#pragma unroll
        for (int st = 0; st < 4; st++) {
          float4v s = {};
          s = __builtin_amdgcn_mfma_f32_16x16x32_bf16(qf[f][0], kf[st][0], s, 0, 0, 0);
          s = __builtin_amdgcn_mfma_f32_16x16x32_bf16(qf[f][1], kf[st][1], s, 0, 0, 0);
          sc[f][st] = s;
        }

      // V fragments
      short8 vf[2][4];
#pragma unroll
      for (int ks = 0; ks < 2; ks++)
#pragma unroll
        for (int ni = 0; ni < 4; ni++)
          vf[ks][ni] = *(const short8*)&Vts[half * 2 + ks][ni * 16 + row16][oct * 8];

      // p = exp2(fma(s, log2e, bias')); bias reads paired for ds_read2_b32
#pragma unroll
      for (int f = 0; f < 2; f++) {
        const int base = kt + half * 64 + row16 - wid * 32 - f * 16 - oct * 4 + 127;
#pragma unroll
        for (int r = 0; r < 4; r++) {
          const int i0 = base - r;
          float b0 = biasS[i0],      b1 = biasS[i0 + 16];
          float b2 = biasS[i0 + 32], b3 = biasS[i0 + 48];
          sc[f][0][r] = __builtin_amdgcn_exp2f(__builtin_fmaf(sc[f][0][r], L2E, b0));
          sc[f][1][r] = __builtin_amdgcn_exp2f(__builtin_fmaf(sc[f][1][r], L2E, b1));
          sc[f][2][r] = __builtin_amdgcn_exp2f(__builtin_fmaf(sc[f][2][r], L2E, b2));
          sc[f][3][r] = __builtin_amdgcn_exp2f(__builtin_fmaf(sc[f][3][r], L2E, b3));
        }
#pragma unroll
        for (int r = 0; r < 4; r++)
          l_r[f][r] += (sc[f][0][r] + sc[f][1][r]) + (sc[f][2][r] + sc[f][3][r]);
      }

      // P roundtrip + PV (per f; Pl reuse across f is safe: same-wave DS in order)
#pragma unroll
      for (int f = 0; f < 2; f++) {
#pragma unroll
        for (int ks = 0; ks < 2; ks++)
#pragma unroll
          for (int r = 0; r < 4; r++) {
            uint32_t pk = (uint32_t)f2b_fast(sc[f][2 * ks][r]) |
                          ((uint32_t)f2b_fast(sc[f][2 * ks + 1][r]) << 16);
            *(uint32_t*)&Pl[wid][ks][oct * 4 + r][2 * row16] = pk;
          }
#pragma unroll
        for (int ks = 0; ks < 2; ks++) {
          short8 pf = *(const short8*)&Pl[wid][ks][row16][oct * 8];
#pragma unroll
          for (int ni = 0; ni < 4; ni++)
            o_acc[f][ni] = __builtin_amdgcn_mfma_f32_16x16x32_bf16(pf, vf[ks][ni], o_acc[f][ni], 0, 0, 0);
        }
      }
    }
  }

  // normalize + store
#pragma unroll
  for (int f = 0; f < 2; f++) {
#pragma unroll
    for (int r = 0; r < 4; r++) {
      float v = l_r[f][r];
      v += __shfl_xor(v, 1); v += __shfl_xor(v, 2);
      v += __shfl_xor(v, 4); v += __shfl_xor(v, 8);
      l_r[f][r] = 1.0f / v;
    }
    const size_t orow = (size_t)b * S + qt0 + wid * 32 + f * 16 + oct * 4;
#pragma unroll
    for (int ni = 0; ni < 4; ni++)
#pragma unroll
      for (int r = 0; r < 4; r++)
        ctx[(orow + r) * 1024 + h * 64 + ni * 16 + row16] = f2b_fast(o_acc[f][ni][r] * l_r[f][r]);
  }
}

// ---------------- host launcher ------------------------------------------------
extern "C" void kernel_launch(void* const* d_in, const int* in_sizes, int n_in,
                              void* d_out, int out_size, void* d_ws, size_t ws_size,
                              hipStream_t stream) {
  const float* x        = (const float*)d_in[0];
  const float* q_w      = (const float*)d_in[1];
  const float* k_w      = (const float*)d_in[2];
  const float* v_w      = (const float*)d_in[3];
  const float* o_w      = (const float*)d_in[4];
  const float* rel_bias = (const float*)d_in[5];

  char* ws = (char*)d_ws;
  u16*   xb    = (u16*)(ws);                         // 4096*1024 bf16 (8 MB)
  u16*   wqkv  = (u16*)(ws + 8388608);               // 3072*1024      (6 MB)
  u16*   owb   = (u16*)(ws + 14680064);               // 1024*1024      (2 MB)
  u16*   qkvb  = (u16*)(ws + 16777216);              // 4096*3072      (24 MB)
  u16*   ctxb  = (u16*)(ws + 41943040);              // 4096*1024      (8 MB)
  float* biasT = (float*)(ws + 50331648);            // 16*4096        (256 KB)
  u16*   vTp   = xb;                                 // reuse xb after QKV GEMM

  cvt_all<<<8192, 256, 0, stream>>>(x, q_w, k_w, v_w, o_w, xb, wqkv, owb);
  build_bias<<<256, 256, 0, stream>>>(rel_bias, biasT);

  dim3 g1(4096 / 128, 3072 / 128);
  gemm_bt<true><<<g1, 256, 0, stream>>>(xb, wqkv, qkvb, 1024, 3072);

  dim3 gt(2048 / 64, 16, 2);
  transpose_v<<<gt, 256, 0, stream>>>(qkvb, vTp);    // overwrites xb (done with it)

  dim3 g2(2048 / 128, 16, 2);
  flash_attn<<<g2, 256, 0, stream>>>(qkvb, vTp, biasT, ctxb);

  dim3 g3(4096 / 128, 1024 / 128);
  gemm_bt<false><<<g3, 256, 0, stream>>>(ctxb, owb, d_out, 1024, 1024);
}

// Round 6
// 205.293 us; speedup vs baseline: 1.0880x; 1.0880x over previous
//
#include <hip/hip_runtime.h>
#include <stdint.h>

// T5-style attention, MI355X gfx950.
// B=2 S=2048 D=1024 H=16 DK=64, NUM_BUCKETS=32, MAX_DISTANCE=128.
// R6: R4 structure (KT=64, no spills) + exp2 fold (log2e baked into bias
// table) + paired bias reads + f-interleaved P/exp ordering.

typedef unsigned short u16;
typedef __attribute__((ext_vector_type(8))) short short8;
typedef __attribute__((ext_vector_type(4))) float float4v;
typedef __attribute__((ext_vector_type(4))) u16 ushort4v;

typedef __attribute__((address_space(1))) void void_g;
typedef __attribute__((address_space(3))) void void_l;

#define L2E 1.4426950408889634f

__device__ __forceinline__ u16 f2b(float f) {
  union { float f; uint32_t u; } v; v.f = f;
  uint32_t r = (v.u + 0x7fffu + ((v.u >> 16) & 1u)) >> 16;
  return (u16)r;
}
__device__ __forceinline__ u16 f2b_fast(float f) {
  union { float f; uint32_t u; } v; v.f = f;
  return (u16)((v.u + 0x8000u) >> 16);
}

// ---------------- fused fp32 -> bf16 convert -----------------------------------
__global__ void cvt_all(const float* __restrict__ x,  const float* __restrict__ qw,
                        const float* __restrict__ kw, const float* __restrict__ vw,
                        const float* __restrict__ ow,
                        u16* __restrict__ xb, u16* __restrict__ wqkv, u16* __restrict__ owb) {
  int i = blockIdx.x * blockDim.x + threadIdx.x;
  const float* s; u16* d; int off;
  if (i < 1048576)      { s = x;  d = xb;              off = i; }
  else if (i < 1310720) { s = qw; d = wqkv;            off = i - 1048576; }
  else if (i < 1572864) { s = kw; d = wqkv + 1048576;  off = i - 1310720; }
  else if (i < 1835008) { s = vw; d = wqkv + 2097152;  off = i - 1572864; }
  else                  { s = ow; d = owb;             off = i - 1835008; }
  float4v v = ((const float4v*)s)[off];
  ushort4v o;
  o.x = f2b(v.x); o.y = f2b(v.y); o.z = f2b(v.z); o.w = f2b(v.w);
  ((ushort4v*)d)[off] = o;
}

// ---------------- bias table: biasT[h][d+2047] = (bias - 8) * log2e ------------
__global__ void build_bias(const float* __restrict__ rel_bias, float* __restrict__ biasT) {
  int idx = blockIdx.x * blockDim.x + threadIdx.x; // 16 * 4096
  int h = idx >> 12, t = idx & 4095;
  if (t > 4094) { biasT[h * 4096 + 4095] = -1.0e4f; return; }  // loaded, never used
  int d = t - 2047;
  int n = -d;
  int ret = (n < 0) ? 16 : 0;
  int na = (n < 0) ? -n : n;
  int bucket;
  if (na < 8) {
    bucket = ret + na;
  } else {
    float v = logf((float)na / 8.0f) / logf(16.0f) * 8.0f;
    int vi = 8 + (int)v;
    bucket = ret + (vi > 15 ? 15 : vi);
  }
  biasT[h * 4096 + t] = (rel_bias[bucket * 16 + h] - 8.0f) * L2E;
}

// ---------------- bf16 GEMM: C[M,N] = A[M,K] * W[N,K]^T ------------------------
template<bool OUT_BF16>
__global__ __launch_bounds__(256, 2)
void gemm_bt(const u16* __restrict__ A, const u16* __restrict__ W,
             void* __restrict__ Cp, int K, int N) {
  __shared__ __align__(16) u16 As[128 * 32];
  __shared__ __align__(16) u16 Bs[128 * 32];
  const int tid = threadIdx.x;
  const int wid = tid >> 6;
  const int lane = tid & 63;
  const int row16 = lane & 15, oct = lane >> 4;
  const int tm = blockIdx.x * 128, tn = blockIdx.y * 128;
  const int wm = (wid & 1) * 64, wn = (wid >> 1) * 64;
  float4v acc[4][4] = {};
  for (int k0 = 0; k0 < K; k0 += 32) {
    __syncthreads();
#pragma unroll
    for (int i = 0; i < 2; i++) {
      const int fo = (i * 256 + tid) * 8;
      const int r = fo >> 5, c = fo & 31;
      __builtin_amdgcn_global_load_lds((void_g*)(A + (size_t)(tm + r) * K + k0 + c),
                                       (void_l*)(As + (i * 256 + wid * 64) * 8), 16, 0, 0);
      __builtin_amdgcn_global_load_lds((void_g*)(W + (size_t)(tn + r) * K + k0 + c),
                                       (void_l*)(Bs + (i * 256 + wid * 64) * 8), 16, 0, 0);
    }
    __syncthreads();
    short8 af[4], bfr[4];
#pragma unroll
    for (int mi = 0; mi < 4; mi++)
      af[mi] = *(const short8*)(As + (wm + mi * 16 + row16) * 32 + oct * 8);
#pragma unroll
    for (int ni = 0; ni < 4; ni++)
      bfr[ni] = *(const short8*)(Bs + (wn + ni * 16 + row16) * 32 + oct * 8);
#pragma unroll
    for (int mi = 0; mi < 4; mi++)
#pragma unroll
      for (int ni = 0; ni < 4; ni++)
        acc[mi][ni] = __builtin_amdgcn_mfma_f32_16x16x32_bf16(af[mi], bfr[ni], acc[mi][ni], 0, 0, 0);
  }
#pragma unroll
  for (int mi = 0; mi < 4; mi++) {
    const int rbase = tm + wm + mi * 16 + oct * 4;
#pragma unroll
    for (int ni = 0; ni < 4; ni++) {
      const int col = tn + wn + ni * 16 + row16;
#pragma unroll
      for (int r = 0; r < 4; r++) {
        size_t idx = (size_t)(rbase + r) * N + col;
        if (OUT_BF16) ((u16*)Cp)[idx] = f2b(acc[mi][ni][r]);
        else          ((float*)Cp)[idx] = acc[mi][ni][r];
      }
    }
  }
}

// ---------------- V transpose + k-permutation ----------------------------------
// QKV V-section [b][s][h*64+d] -> vTp[b][h][d][s'], kappa = 2*(s&15)+((s>>4)&1)
__global__ __launch_bounds__(256, 2)
void transpose_v(const u16* __restrict__ QKV, u16* __restrict__ vTp) {
  const int s0 = blockIdx.x * 64, h = blockIdx.y, b = blockIdx.z;
  const int tid = threadIdx.x;
  __shared__ u16 T[64 * 73];
  const u16* src = QKV + 2048 + (size_t)b * 2048 * 3072 + h * 64;
#pragma unroll
  for (int it = 0; it < 2; it++) {
    int idx = it * 256 + tid;
    int sl = idx >> 3;
    int c = idx & 7;
    short8 v = *(const short8*)(src + (size_t)(s0 + sl) * 3072 + c * 8);
#pragma unroll
    for (int k = 0; k < 8; k++) T[(c * 8 + k) * 73 + sl] = (u16)v[k];
  }
  __syncthreads();
  u16* dst = vTp + ((size_t)(b * 16 + h) * 64) * 2048 + s0;
#pragma unroll
  for (int it = 0; it < 2; it++) {
    int idx = it * 256 + tid;
    int d = idx >> 3;
    int cs = idx & 7;
    short8 o;
#pragma unroll
    for (int k = 0; k < 8; k++) {
      int sp = cs * 8 + k;
      int sl = (sp & 32) + 16 * (sp & 1) + ((sp & 31) >> 1);
      o[k] = (short)T[d * 73 + sl];
    }
    *(short8*)(dst + (size_t)d * 2048 + cs * 8) = o;
  }
}

// ---------------- flash attention v5 -------------------------------------------
// grid (S/128, H, B), block 256 = 4 waves; wave owns 32 q-rows (2 q-frags).
// KT=64. Static softmax max 8, exp2-folded bias ((b-8)*log2e in table).
__global__ __launch_bounds__(256, 2)
void flash_attn(const u16* __restrict__ QKV, const u16* __restrict__ vTp,
                const float* __restrict__ biasT, u16* __restrict__ ctx) {
  const int S = 2048, LDQ = 3072;
  const int qt0 = blockIdx.x * 128;
  const int h = blockIdx.y, b = blockIdx.z;
  const int tid = threadIdx.x, wid = tid >> 6, lane = tid & 63;
  const int row16 = lane & 15, oct = lane >> 4;

  __shared__ __align__(16) float biasS[2176];        // 8.5 KB (pre *log2e, -8 folded)
  __shared__ __align__(16) u16 Ks[2][64][40];        // 10 KB
  __shared__ __align__(16) u16 Vts[2][64][40];       // 10 KB
  __shared__ __align__(16) u16 Pl[4][2][16][40];     // 10 KB per-wave P staging

  {
    const float* bsrc = biasT + h * 4096 + (1920 - qt0);
    for (int i = tid; i < 544; i += 256)
      ((float4v*)biasS)[i] = ((const float4v*)bsrc)[i];
  }

  const u16* qbase = QKV + ((size_t)b * S + qt0 + wid * 32) * LDQ + h * 64;
  short8 qf[2][2];
#pragma unroll
  for (int f = 0; f < 2; f++)
#pragma unroll
    for (int hd = 0; hd < 2; hd++)
      qf[f][hd] = *(const short8*)(qbase + (size_t)(f * 16 + row16) * LDQ + hd * 32 + oct * 8);

  float l_r[2][4] = {};
  float4v o_acc[2][4] = {};

  const int sr = lane >> 2, c8 = (lane & 3) * 8;
  const int srow = wid * 16 + sr;
  const u16* Kst = QKV + 1024 + ((size_t)b * S + srow) * LDQ + h * 64 + c8;
  const u16* Vst = vTp + ((size_t)(b * 16 + h) * 64 + srow) * 2048 + c8;

  short8 kreg[2], vreg[2];
#pragma unroll
  for (int hd = 0; hd < 2; hd++) kreg[hd] = *(const short8*)(Kst + hd * 32);
#pragma unroll
  for (int ks = 0; ks < 2; ks++) vreg[ks] = *(const short8*)(Vst + ks * 32);

  for (int kt = 0; kt < S; kt += 64) {
    __syncthreads();
#pragma unroll
    for (int hd = 0; hd < 2; hd++) *(short8*)&Ks[hd][srow][c8] = kreg[hd];
#pragma unroll
    for (int ks = 0; ks < 2; ks++) *(short8*)&Vts[ks][srow][c8] = vreg[ks];
    __syncthreads();

    if (kt + 64 < S) {
#pragma unroll
      for (int hd = 0; hd < 2; hd++)
        kreg[hd] = *(const short8*)(Kst + (size_t)(kt + 64) * LDQ + hd * 32);
#pragma unroll
      for (int ks = 0; ks < 2; ks++)
        vreg[ks] = *(const short8*)(Vst + (kt + 64) + ks * 32);
    }

    short8 kf[4][2];
#pragma unroll
    for (int st = 0; st < 4; st++)
#pragma unroll
      for (int hd = 0; hd < 2; hd++)
        kf[st][hd] = *(const short8*)&Ks[hd][st * 16 + row16][oct * 8];

    float4v sc[2][4];
#pragma unroll
    for (int f = 0; f < 2; f++)
#pragma unroll
      for (int st = 0; st < 4; st++) {
        float4v s = {};
        s = __builtin_amdgcn_mfma_f32_16x16x32_bf16(qf[f][0], kf[st][0], s, 0, 0, 0);
        s = __builtin_amdgcn_mfma_f32_16x16x32_bf16(qf[f][1], kf[st][1], s, 0, 0, 0);
        sc[f][st] = s;
      }

    short8 vf[2][4];
#pragma unroll
    for (int ks = 0; ks < 2; ks++)
#pragma unroll
      for (int ni = 0; ni < 4; ni++)
        vf[ks][ni] = *(const short8*)&Vts[ks][ni * 16 + row16][oct * 8];

    // exp f0 -> P-store f0 -> exp f1 (hides f0 store latency) -> PV f0
    // -> P-store f1 -> PV f1.  (Pl wave-local; DS pipe in-order.)
#pragma unroll
    for (int f = 0; f < 2; f++) {
      const int base = kt + row16 - wid * 32 - f * 16 - oct * 4 + 127;
#pragma unroll
      for (int r = 0; r < 4; r++) {
        const int i0 = base - r;
        float b0 = biasS[i0],      b1 = biasS[i0 + 16];
        float b2 = biasS[i0 + 32], b3 = biasS[i0 + 48];
        sc[f][0][r] = __builtin_amdgcn_exp2f(__builtin_fmaf(sc[f][0][r], L2E, b0));
        sc[f][1][r] = __builtin_amdgcn_exp2f(__builtin_fmaf(sc[f][1][r], L2E, b1));
        sc[f][2][r] = __builtin_amdgcn_exp2f(__builtin_fmaf(sc[f][2][r], L2E, b2));
        sc[f][3][r] = __builtin_amdgcn_exp2f(__builtin_fmaf(sc[f][3][r], L2E, b3));
      }
      if (f == 0) {
#pragma unroll
        for (int ks = 0; ks < 2; ks++)
#pragma unroll
          for (int r = 0; r < 4; r++) {
            uint32_t pk = (uint32_t)f2b_fast(sc[0][2 * ks][r]) |
                          ((uint32_t)f2b_fast(sc[0][2 * ks + 1][r]) << 16);
            *(uint32_t*)&Pl[wid][ks][oct * 4 + r][2 * row16] = pk;
          }
      }
    }
#pragma unroll
    for (int f = 0; f < 2; f++) {
      if (f == 1) {
#pragma unroll
        for (int ks = 0; ks < 2; ks++)
#pragma unroll
          for (int r = 0; r < 4; r++) {
            uint32_t pk = (uint32_t)f2b_fast(sc[1][2 * ks][r]) |
                          ((uint32_t)f2b_fast(sc[1][2 * ks + 1][r]) << 16);
            *(uint32_t*)&Pl[wid][ks][oct * 4 + r][2 * row16] = pk;
          }
      }
#pragma unroll
      for (int r = 0; r < 4; r++)
        l_r[f][r] += (sc[f][0][r] + sc[f][1][r]) + (sc[f][2][r] + sc[f][3][r]);
#pragma unroll
      for (int ks = 0; ks < 2; ks++) {
        short8 pf = *(const short8*)&Pl[wid][ks][row16][oct * 8];
#pragma unroll
        for (int ni = 0; ni < 4; ni++)
          o_acc[f][ni] = __builtin_amdgcn_mfma_f32_16x16x32_bf16(pf, vf[ks][ni], o_acc[f][ni], 0, 0, 0);
      }
    }
  }

#pragma unroll
  for (int f = 0; f < 2; f++) {
#pragma unroll
    for (int r = 0; r < 4; r++) {
      float v = l_r[f][r];
      v += __shfl_xor(v, 1); v += __shfl_xor(v, 2);
      v += __shfl_xor(v, 4); v += __shfl_xor(v, 8);
      l_r[f][r] = 1.0f / v;
    }
    const size_t orow = (size_t)b * S + qt0 + wid * 32 + f * 16 + oct * 4;
#pragma unroll
    for (int ni = 0; ni < 4; ni++)
#pragma unroll
      for (int r = 0; r < 4; r++)
        ctx[(orow + r) * 1024 + h * 64 + ni * 16 + row16] = f2b_fast(o_acc[f][ni][r] * l_r[f][r]);
  }
}

// ---------------- host launcher ------------------------------------------------
extern "C" void kernel_launch(void* const* d_in, const int* in_sizes, int n_in,
                              void* d_out, int out_size, void* d_ws, size_t ws_size,
                              hipStream_t stream) {
  const float* x        = (const float*)d_in[0];
  const float* q_w      = (const float*)d_in[1];
  const float* k_w      = (const float*)d_in[2];
  const float* v_w      = (const float*)d_in[3];
  const float* o_w      = (const float*)d_in[4];
  const float* rel_bias = (const float*)d_in[5];

  char* ws = (char*)d_ws;
  u16*   xb    = (u16*)(ws);                         // 8 MB
  u16*   wqkv  = (u16*)(ws + 8388608);               // 6 MB
  u16*   owb   = (u16*)(ws + 14680064);              // 2 MB
  u16*   qkvb  = (u16*)(ws + 16777216);              // 24 MB
  u16*   ctxb  = (u16*)(ws + 41943040);              // 8 MB
  float* biasT = (float*)(ws + 50331648);            // 256 KB
  u16*   vTp   = xb;                                 // reuse xb after QKV GEMM

  cvt_all<<<8192, 256, 0, stream>>>(x, q_w, k_w, v_w, o_w, xb, wqkv, owb);
  build_bias<<<256, 256, 0, stream>>>(rel_bias, biasT);

  dim3 g1(4096 / 128, 3072 / 128);
  gemm_bt<true><<<g1, 256, 0, stream>>>(xb, wqkv, qkvb, 1024, 3072);

  dim3 gt(2048 / 64, 16, 2);
  transpose_v<<<gt, 256, 0, stream>>>(qkvb, vTp);

  dim3 g2(2048 / 128, 16, 2);
  flash_attn<<<g2, 256, 0, stream>>>(qkvb, vTp, biasT, ctxb);

  dim3 g3(4096 / 128, 1024 / 128);
  gemm_bt<false><<<g3, 256, 0, stream>>>(ctxb, owb, d_out, 1024, 1024);
}